// Round 7
// baseline (1210.150 us; speedup 1.0000x reference)
//
#include <hip/hip_runtime.h>

#define N_    16
#define M_    20000
#define FIN_  64
#define K_    4
#define NNZ_  320000
#define KM_   (K_ * M_)        // 80000
#define KNNZ_ (K_ * NNZ_)      // 1280000
#define CAP_  64               // Poisson(16): P(>64) ~ 1e-19 per bucket

// out[((n*M+m)*FIN+f)*K + k] = relu( x[n,m,f] + sum_{e: rows[k,e]==m} vals[k,e]*x[n,cols[k,e],f] )

// ws layout, tier A:
//   xt    [M_][2][FIN_][8] bf16 @ 0            (xt[m][h][f][n8]; 1KB per (m,h), 2KB per m)
//   cnt   [KM_]        int  @ XT_BYTES
//   slots [KM_*CAP_]   uint @ XT_BYTES+CNT_BYTES   (bf16(val)<<16 | col)
#define XT_BYTES   ((size_t)M_ * FIN_ * N_ * 2)        // 40,960,000
#define CNT_BYTES  ((size_t)KM_ * 4)                   // 320,000
#define SLOT_BYTES ((size_t)KM_ * CAP_ * 4)            // 20,480,000
#define WS_A (XT_BYTES + CNT_BYTES + SLOT_BYTES)       // 61,760,000
#define WS_B (CNT_BYTES + SLOT_BYTES)

__device__ __forceinline__ unsigned bf16bits(float v) {
    unsigned u = __float_as_uint(v);
    return (u + 0x7FFFu + ((u >> 16) & 1u)) & 0xFFFF0000u;   // RNE bf16 in high 16
}

// ---------------- transpose + cnt zeroing ----------------
__global__ __launch_bounds__(256) void transpose_kernel(const float* __restrict__ x,
                                                        uint4* __restrict__ xt4,
                                                        int* __restrict__ cnt) {
    int gtid = blockIdx.x * 256 + threadIdx.x;
    if (gtid < KM_) cnt[gtid] = 0;

    int wid = threadIdx.x >> 6, f = threadIdx.x & 63;
    int m = blockIdx.x * 4 + wid;
    unsigned h[16];
    #pragma unroll
    for (int n = 0; n < N_; ++n)
        h[n] = bf16bits(x[((size_t)n * M_ + m) * FIN_ + f]) >> 16;
    uint4 A, B;
    A.x = h[0]  | (h[1]  << 16); A.y = h[2]  | (h[3]  << 16);
    A.z = h[4]  | (h[5]  << 16); A.w = h[6]  | (h[7]  << 16);
    B.x = h[8]  | (h[9]  << 16); B.y = h[10] | (h[11] << 16);
    B.z = h[12] | (h[13] << 16); B.w = h[14] | (h[15] << 16);
    xt4[m * 128 + f]      = A;   // h = 0 (n 0..7)
    xt4[m * 128 + 64 + f] = B;   // h = 1 (n 8..15)
}

// ---------------- binning ----------------
__global__ void bin_kernel(const float* __restrict__ vals,
                           const int*   __restrict__ rows,
                           const int*   __restrict__ cols,
                           int*      __restrict__ cnt,
                           unsigned* __restrict__ slots) {
    int idx = blockIdx.x * blockDim.x + threadIdx.x;
    if (idx >= KNNZ_) return;
    int k = idx / NNZ_;
    int b = k * M_ + rows[idx];
    int rank = atomicAdd(&cnt[b], 1);
    if (rank < CAP_)
        slots[(size_t)b * CAP_ + rank] = bf16bits(vals[idx]) | (unsigned)cols[idx];
}

// ---------------- tier A gather: ping-pong pipelined 8-entry groups ----------------
__device__ __forceinline__ void fma8(float* a, float v, uint4 U) {
    a[0] += v * __uint_as_float(U.x << 16);
    a[1] += v * __uint_as_float(U.x & 0xFFFF0000u);
    a[2] += v * __uint_as_float(U.y << 16);
    a[3] += v * __uint_as_float(U.y & 0xFFFF0000u);
    a[4] += v * __uint_as_float(U.z << 16);
    a[5] += v * __uint_as_float(U.z & 0xFFFF0000u);
    a[6] += v * __uint_as_float(U.w << 16);
    a[7] += v * __uint_as_float(U.w & 0xFFFF0000u);
}

#define ISSUE(G, U, V)                                                          \
    do {                                                                        \
        _Pragma("unroll")                                                       \
        for (int i_ = 0; i_ < 8; ++i_) {                                        \
            int s_ = ((G) + i_ < cn) ? __shfl((int)sl, (G) + i_, 64) : 0;       \
            V[i_] = __uint_as_float((unsigned)s_ & 0xFFFF0000u);                \
            U[i_] = *(const uint4*)(rowbase +                                   \
                        ((size_t)((unsigned)s_ & 0xFFFFu) << 11));              \
        }                                                                       \
    } while (0)

#define FMAG(ACC, U, V)                                                         \
    do {                                                                        \
        _Pragma("unroll")                                                       \
        for (int i_ = 0; i_ < 8; ++i_) fma8(ACC, V[i_], U[i_]);                 \
    } while (0)

__global__ __launch_bounds__(256, 4) void gather_bf16_kernel(const char* __restrict__ xtb,
                                                             const int* __restrict__ cnt_arr,
                                                             const unsigned* __restrict__ slots,
                                                             float4* __restrict__ out4) {
    int wid = threadIdx.x >> 6;
    int f   = threadIdx.x & 63;
    int m   = blockIdx.x * 2 + (wid >> 1);
    int hh  = wid & 1;                          // n-half: n = hh*8 + j
    const char* rowbase = xtb + hh * 1024 + f * 16;   // + c*2048 -> this thread's 16B

    float acc[K_][8];
    {   // identity term
        uint4 X = *(const uint4*)(rowbase + ((size_t)m << 11));
        float xv[8];
        xv[0]=__uint_as_float(X.x<<16); xv[1]=__uint_as_float(X.x&0xFFFF0000u);
        xv[2]=__uint_as_float(X.y<<16); xv[3]=__uint_as_float(X.y&0xFFFF0000u);
        xv[4]=__uint_as_float(X.z<<16); xv[5]=__uint_as_float(X.z&0xFFFF0000u);
        xv[6]=__uint_as_float(X.w<<16); xv[7]=__uint_as_float(X.w&0xFFFF0000u);
        #pragma unroll
        for (int k = 0; k < K_; ++k)
            #pragma unroll
            for (int j = 0; j < 8; ++j) acc[k][j] = xv[j];
    }

    #pragma unroll
    for (int k = 0; k < K_; ++k) {
        int b  = k * M_ + m;
        int cn = cnt_arr[b];
        if (cn > CAP_) cn = CAP_;
        unsigned sl = slots[(size_t)b * CAP_ + f];   // lane l holds slot l

        uint4 uA[8], uB[8];
        float vA[8], vB[8];
        ISSUE(0, uA, vA);                        // prologue: group 0 in flight
        for (int g = 0; g < cn; g += 16) {
            if (g + 8 < cn)  ISSUE(g + 8, uB, vB);    // next group's loads first
            FMAG(acc[k], uA, vA);                     // waits vmcnt(8), not 0
            if (g + 16 < cn) ISSUE(g + 16, uA, vA);
            if (g + 8 < cn)  FMAG(acc[k], uB, vB);
        }
    }

    #pragma unroll
    for (int j = 0; j < 8; ++j) {
        int n = hh * 8 + j;
        float4 w;
        w.x = fmaxf(acc[0][j], 0.0f);
        w.y = fmaxf(acc[1][j], 0.0f);
        w.z = fmaxf(acc[2][j], 0.0f);
        w.w = fmaxf(acc[3][j], 0.0f);
        out4[((size_t)n * M_ + m) * FIN_ + f] = w;
    }
}

// ---------------- tier B gather: f32 x directly ----------------
__global__ __launch_bounds__(256) void gather_f32_kernel(const float* __restrict__ x,
                                                         const int* __restrict__ cnt,
                                                         const unsigned* __restrict__ slots,
                                                         float4* __restrict__ out4) {
    int wid = threadIdx.x >> 6;
    int f   = threadIdx.x & 63;
    int m   = blockIdx.x * 4 + wid;

    float acc[K_][N_];
    #pragma unroll
    for (int n = 0; n < N_; ++n) {
        float xv = x[((size_t)n * M_ + m) * FIN_ + f];
        #pragma unroll
        for (int k = 0; k < K_; ++k) acc[k][n] = xv;
    }

    #pragma unroll
    for (int k = 0; k < K_; ++k) {
        int b  = k * M_ + m;
        int cn = cnt[b];
        if (cn > CAP_) cn = CAP_;
        unsigned sl = slots[(size_t)b * CAP_ + f];
        for (int j = 0; j < cn; ++j) {
            int s = __shfl((int)sl, j, 64);
            float v = __uint_as_float((unsigned)s & 0xFFFF0000u);
            int   c = (int)((unsigned)s & 0xFFFFu);
            const float* xp = x + (size_t)c * FIN_ + f;
            #pragma unroll
            for (int n = 0; n < N_; ++n)
                acc[k][n] += v * xp[(size_t)n * (M_ * FIN_)];
        }
    }

    #pragma unroll
    for (int n = 0; n < N_; ++n) {
        float4 w;
        w.x = fmaxf(acc[0][n], 0.0f);
        w.y = fmaxf(acc[1][n], 0.0f);
        w.z = fmaxf(acc[2][n], 0.0f);
        w.w = fmaxf(acc[3][n], 0.0f);
        out4[((size_t)n * M_ + m) * FIN_ + f] = w;
    }
}

__global__ void zero_cnt_kernel(int* __restrict__ cnt) {
    int i = blockIdx.x * blockDim.x + threadIdx.x;
    if (i < KM_) cnt[i] = 0;
}

// ---------------- tier C: atomic fallback ----------------
__global__ void init_out_kernel(const float* __restrict__ x, float* __restrict__ out) {
    int i = blockIdx.x * blockDim.x + threadIdx.x;
    const int tot = N_ * M_ * FIN_;
    if (i < tot) {
        float v = x[i];
        reinterpret_cast<float4*>(out)[i] = make_float4(v, v, v, v);
    }
}

__global__ void scatter_kernel(const float* __restrict__ x,
                               const float* __restrict__ vals,
                               const int*   __restrict__ rows,
                               const int*   __restrict__ cols,
                               float* __restrict__ out) {
    long long idx = (long long)blockIdx.x * blockDim.x + threadIdx.x;
    int f  = (int)(idx & 63);
    int ea = (int)(idx >> 6);
    if (ea >= KNNZ_) return;
    int k = ea / NNZ_;
    float v = vals[ea];
    int r = rows[ea];
    int c = cols[ea];
    const float* xp = x   + (size_t)c * FIN_ + f;
    float*       op = out + ((size_t)r * FIN_ + f) * K_ + k;
    #pragma unroll
    for (int n = 0; n < N_; ++n)
        atomicAdd(op + (size_t)n * (M_ * FIN_ * K_), v * xp[(size_t)n * (M_ * FIN_)]);
}

__global__ void relu_kernel(float* __restrict__ out) {
    int i = blockIdx.x * blockDim.x + threadIdx.x;
    const int tot4 = (N_ * M_ * FIN_ * K_) / 4;
    if (i < tot4) {
        float4 v = reinterpret_cast<float4*>(out)[i];
        v.x = fmaxf(v.x, 0.0f); v.y = fmaxf(v.y, 0.0f);
        v.z = fmaxf(v.z, 0.0f); v.w = fmaxf(v.w, 0.0f);
        reinterpret_cast<float4*>(out)[i] = v;
    }
}

// ---------------- launch ----------------
extern "C" void kernel_launch(void* const* d_in, const int* in_sizes, int n_in,
                              void* d_out, int out_size, void* d_ws, size_t ws_size,
                              hipStream_t stream) {
    const float* x    = (const float*)d_in[0];
    const float* vals = (const float*)d_in[1];
    const int*   rows = (const int*)d_in[2];
    const int*   cols = (const int*)d_in[3];
    float*       out  = (float*)d_out;
    char*        ws   = (char*)d_ws;

    if (ws_size >= WS_A) {
        uint4*    xt4   = (uint4*)ws;
        int*      cnt   = (int*)(ws + XT_BYTES);
        unsigned* slots = (unsigned*)(ws + XT_BYTES + CNT_BYTES);

        transpose_kernel<<<M_ / 4, 256, 0, stream>>>(x, xt4, cnt);
        bin_kernel<<<(KNNZ_ + 255) / 256, 256, 0, stream>>>(vals, rows, cols, cnt, slots);
        gather_bf16_kernel<<<M_ / 2, 256, 0, stream>>>((const char*)ws, cnt, slots, (float4*)out);
    } else if (ws_size >= WS_B) {
        int*      cnt   = (int*)ws;
        unsigned* slots = (unsigned*)(ws + CNT_BYTES);

        zero_cnt_kernel<<<(KM_ + 255) / 256, 256, 0, stream>>>(cnt);
        bin_kernel<<<(KNNZ_ + 255) / 256, 256, 0, stream>>>(vals, rows, cols, cnt, slots);
        gather_f32_kernel<<<M_ / 4, 256, 0, stream>>>(x, cnt, slots, (float4*)out);
    } else {
        init_out_kernel<<<(N_ * M_ * FIN_ + 255) / 256, 256, 0, stream>>>(x, out);
        {
            long long tot = (long long)KNNZ_ * 64;
            scatter_kernel<<<(int)((tot + 255) / 256), 256, 0, stream>>>(x, vals, rows, cols, out);
        }
        relu_kernel<<<(N_ * M_ * FIN_ * K_ / 4 + 255) / 256, 256, 0, stream>>>(out);
    }
}

// Round 9
// 485.501 us; speedup vs baseline: 2.4926x; 2.4926x over previous
//
#include <hip/hip_runtime.h>

#define N_    16
#define M_    20000
#define FIN_  64
#define K_    4
#define NNZ_  320000
#define KM_   (K_ * M_)        // 80000
#define KNNZ_ (K_ * NNZ_)      // 1280000
#define CAP_  64               // Poisson(16): P(>64) ~ 1e-19 per bucket

// out[((n*M+m)*FIN+f)*K + k] = relu( x[n,m,f] + sum_{e: rows[k,e]==m} vals[k,e]*x[n,cols[k,e],f] )

// ws layout, tier A:
//   xt    [M_][2][FIN_][8] bf16 @ 0            (xt[m][h][f][n8]; 1KB per (m,h), 2KB per m)
//   cnt   [KM_]        int  @ XT_BYTES
//   slots [KM_*CAP_]   uint @ XT_BYTES+CNT_BYTES   (bf16(val)<<16 | col)
#define XT_BYTES   ((size_t)M_ * FIN_ * N_ * 2)        // 40,960,000
#define CNT_BYTES  ((size_t)KM_ * 4)                   // 320,000
#define SLOT_BYTES ((size_t)KM_ * CAP_ * 4)            // 20,480,000
#define WS_A (XT_BYTES + CNT_BYTES + SLOT_BYTES)       // 61,760,000
#define WS_B (CNT_BYTES + SLOT_BYTES)

__device__ __forceinline__ unsigned bf16bits(float v) {
    unsigned u = __float_as_uint(v);
    return (u + 0x7FFFu + ((u >> 16) & 1u)) & 0xFFFF0000u;   // RNE bf16 in high 16
}

// ---------------- transpose + cnt zeroing ----------------
__global__ __launch_bounds__(256) void transpose_kernel(const float* __restrict__ x,
                                                        uint4* __restrict__ xt4,
                                                        int* __restrict__ cnt) {
    int gtid = blockIdx.x * 256 + threadIdx.x;
    if (gtid < KM_) cnt[gtid] = 0;

    int wid = threadIdx.x >> 6, f = threadIdx.x & 63;
    int m = blockIdx.x * 4 + wid;
    unsigned h[16];
    #pragma unroll
    for (int n = 0; n < N_; ++n)
        h[n] = bf16bits(x[((size_t)n * M_ + m) * FIN_ + f]) >> 16;
    uint4 A, B;
    A.x = h[0]  | (h[1]  << 16); A.y = h[2]  | (h[3]  << 16);
    A.z = h[4]  | (h[5]  << 16); A.w = h[6]  | (h[7]  << 16);
    B.x = h[8]  | (h[9]  << 16); B.y = h[10] | (h[11] << 16);
    B.z = h[12] | (h[13] << 16); B.w = h[14] | (h[15] << 16);
    xt4[m * 128 + f]      = A;   // h = 0 (n 0..7)
    xt4[m * 128 + 64 + f] = B;   // h = 1 (n 8..15)
}

// ---------------- binning ----------------
__global__ void bin_kernel(const float* __restrict__ vals,
                           const int*   __restrict__ rows,
                           const int*   __restrict__ cols,
                           int*      __restrict__ cnt,
                           unsigned* __restrict__ slots) {
    int idx = blockIdx.x * blockDim.x + threadIdx.x;
    if (idx >= KNNZ_) return;
    int k = idx / NNZ_;
    int b = k * M_ + rows[idx];
    int rank = atomicAdd(&cnt[b], 1);
    if (rank < CAP_)
        slots[(size_t)b * CAP_ + rank] = bf16bits(vals[idx]) | (unsigned)cols[idx];
}

// ---------------- tier A gather: 4-deep ping-pong pipelined groups ----------------
__device__ __forceinline__ void fma8(float* a, float v, uint4 U) {
    a[0] += v * __uint_as_float(U.x << 16);
    a[1] += v * __uint_as_float(U.x & 0xFFFF0000u);
    a[2] += v * __uint_as_float(U.y << 16);
    a[3] += v * __uint_as_float(U.y & 0xFFFF0000u);
    a[4] += v * __uint_as_float(U.z << 16);
    a[5] += v * __uint_as_float(U.z & 0xFFFF0000u);
    a[6] += v * __uint_as_float(U.w << 16);
    a[7] += v * __uint_as_float(U.w & 0xFFFF0000u);
}

#define ISSUE4(G, U, V)                                                         \
    do {                                                                        \
        _Pragma("unroll")                                                       \
        for (int i_ = 0; i_ < 4; ++i_) {                                        \
            int s_ = ((G) + i_ < cn) ? __shfl((int)sl, (G) + i_, 64) : 0;       \
            V[i_] = __uint_as_float((unsigned)s_ & 0xFFFF0000u);                \
            U[i_] = *(const uint4*)(rowbase +                                   \
                        ((size_t)((unsigned)s_ & 0xFFFFu) << 11));              \
        }                                                                       \
    } while (0)

#define FMAG4(ACC, U, V)                                                        \
    do {                                                                        \
        _Pragma("unroll")                                                       \
        for (int i_ = 0; i_ < 4; ++i_) fma8(ACC, V[i_], U[i_]);                 \
    } while (0)

__global__ __launch_bounds__(256, 2) void gather_bf16_kernel(const char* __restrict__ xtb,
                                                             const int* __restrict__ cnt_arr,
                                                             const unsigned* __restrict__ slots,
                                                             float4* __restrict__ out4) {
    int wid = threadIdx.x >> 6;
    int f   = threadIdx.x & 63;
    int m   = blockIdx.x * 2 + (wid >> 1);
    int hh  = wid & 1;                          // n-half: n = hh*8 + j
    const char* rowbase = xtb + hh * 1024 + f * 16;   // + c*2048 -> this thread's 16B

    float acc[K_][8];
    {   // identity term
        uint4 X = *(const uint4*)(rowbase + ((size_t)m << 11));
        float xv[8];
        xv[0]=__uint_as_float(X.x<<16); xv[1]=__uint_as_float(X.x&0xFFFF0000u);
        xv[2]=__uint_as_float(X.y<<16); xv[3]=__uint_as_float(X.y&0xFFFF0000u);
        xv[4]=__uint_as_float(X.z<<16); xv[5]=__uint_as_float(X.z&0xFFFF0000u);
        xv[6]=__uint_as_float(X.w<<16); xv[7]=__uint_as_float(X.w&0xFFFF0000u);
        #pragma unroll
        for (int k = 0; k < K_; ++k)
            #pragma unroll
            for (int j = 0; j < 8; ++j) acc[k][j] = xv[j];
    }

    #pragma unroll
    for (int k = 0; k < K_; ++k) {
        int b  = k * M_ + m;
        int cn = cnt_arr[b];
        if (cn > CAP_) cn = CAP_;
        unsigned sl = slots[(size_t)b * CAP_ + f];   // lane l holds slot l

        uint4 uA[4], uB[4];
        float vA[4], vB[4];
        ISSUE4(0, uA, vA);                       // prologue: group 0 in flight
        for (int g = 0; g < cn; g += 8) {
            if (g + 4 < cn) ISSUE4(g + 4, uB, vB);    // keep next group in flight
            FMAG4(acc[k], uA, vA);
            if (g + 8 < cn) ISSUE4(g + 8, uA, vA);
            if (g + 4 < cn) FMAG4(acc[k], uB, vB);
        }
    }

    #pragma unroll
    for (int j = 0; j < 8; ++j) {
        int n = hh * 8 + j;
        float4 w;
        w.x = fmaxf(acc[0][j], 0.0f);
        w.y = fmaxf(acc[1][j], 0.0f);
        w.z = fmaxf(acc[2][j], 0.0f);
        w.w = fmaxf(acc[3][j], 0.0f);
        out4[((size_t)n * M_ + m) * FIN_ + f] = w;
    }
}

// ---------------- tier B gather: f32 x directly ----------------
__global__ __launch_bounds__(256) void gather_f32_kernel(const float* __restrict__ x,
                                                         const int* __restrict__ cnt,
                                                         const unsigned* __restrict__ slots,
                                                         float4* __restrict__ out4) {
    int wid = threadIdx.x >> 6;
    int f   = threadIdx.x & 63;
    int m   = blockIdx.x * 4 + wid;

    float acc[K_][N_];
    #pragma unroll
    for (int n = 0; n < N_; ++n) {
        float xv = x[((size_t)n * M_ + m) * FIN_ + f];
        #pragma unroll
        for (int k = 0; k < K_; ++k) acc[k][n] = xv;
    }

    #pragma unroll
    for (int k = 0; k < K_; ++k) {
        int b  = k * M_ + m;
        int cn = cnt[b];
        if (cn > CAP_) cn = CAP_;
        unsigned sl = slots[(size_t)b * CAP_ + f];
        for (int j = 0; j < cn; ++j) {
            int s = __shfl((int)sl, j, 64);
            float v = __uint_as_float((unsigned)s & 0xFFFF0000u);
            int   c = (int)((unsigned)s & 0xFFFFu);
            const float* xp = x + (size_t)c * FIN_ + f;
            #pragma unroll
            for (int n = 0; n < N_; ++n)
                acc[k][n] += v * xp[(size_t)n * (M_ * FIN_)];
        }
    }

    #pragma unroll
    for (int n = 0; n < N_; ++n) {
        float4 w;
        w.x = fmaxf(acc[0][n], 0.0f);
        w.y = fmaxf(acc[1][n], 0.0f);
        w.z = fmaxf(acc[2][n], 0.0f);
        w.w = fmaxf(acc[3][n], 0.0f);
        out4[((size_t)n * M_ + m) * FIN_ + f] = w;
    }
}

__global__ void zero_cnt_kernel(int* __restrict__ cnt) {
    int i = blockIdx.x * blockDim.x + threadIdx.x;
    if (i < KM_) cnt[i] = 0;
}

// ---------------- tier C: atomic fallback ----------------
__global__ void init_out_kernel(const float* __restrict__ x, float* __restrict__ out) {
    int i = blockIdx.x * blockDim.x + threadIdx.x;
    const int tot = N_ * M_ * FIN_;
    if (i < tot) {
        float v = x[i];
        reinterpret_cast<float4*>(out)[i] = make_float4(v, v, v, v);
    }
}

__global__ void scatter_kernel(const float* __restrict__ x,
                               const float* __restrict__ vals,
                               const int*   __restrict__ rows,
                               const int*   __restrict__ cols,
                               float* __restrict__ out) {
    long long idx = (long long)blockIdx.x * blockDim.x + threadIdx.x;
    int f  = (int)(idx & 63);
    int ea = (int)(idx >> 6);
    if (ea >= KNNZ_) return;
    int k = ea / NNZ_;
    float v = vals[ea];
    int r = rows[ea];
    int c = cols[ea];
    const float* xp = x   + (size_t)c * FIN_ + f;
    float*       op = out + ((size_t)r * FIN_ + f) * K_ + k;
    #pragma unroll
    for (int n = 0; n < N_; ++n)
        atomicAdd(op + (size_t)n * (M_ * FIN_ * K_), v * xp[(size_t)n * (M_ * FIN_)]);
}

__global__ void relu_kernel(float* __restrict__ out) {
    int i = blockIdx.x * blockDim.x + threadIdx.x;
    const int tot4 = (N_ * M_ * FIN_ * K_) / 4;
    if (i < tot4) {
        float4 v = reinterpret_cast<float4*>(out)[i];
        v.x = fmaxf(v.x, 0.0f); v.y = fmaxf(v.y, 0.0f);
        v.z = fmaxf(v.z, 0.0f); v.w = fmaxf(v.w, 0.0f);
        reinterpret_cast<float4*>(out)[i] = v;
    }
}

// ---------------- launch ----------------
extern "C" void kernel_launch(void* const* d_in, const int* in_sizes, int n_in,
                              void* d_out, int out_size, void* d_ws, size_t ws_size,
                              hipStream_t stream) {
    const float* x    = (const float*)d_in[0];
    const float* vals = (const float*)d_in[1];
    const int*   rows = (const int*)d_in[2];
    const int*   cols = (const int*)d_in[3];
    float*       out  = (float*)d_out;
    char*        ws   = (char*)d_ws;

    if (ws_size >= WS_A) {
        uint4*    xt4   = (uint4*)ws;
        int*      cnt   = (int*)(ws + XT_BYTES);
        unsigned* slots = (unsigned*)(ws + XT_BYTES + CNT_BYTES);

        transpose_kernel<<<M_ / 4, 256, 0, stream>>>(x, xt4, cnt);
        bin_kernel<<<(KNNZ_ + 255) / 256, 256, 0, stream>>>(vals, rows, cols, cnt, slots);
        gather_bf16_kernel<<<M_ / 2, 256, 0, stream>>>((const char*)ws, cnt, slots, (float4*)out);
    } else if (ws_size >= WS_B) {
        int*      cnt   = (int*)ws;
        unsigned* slots = (unsigned*)(ws + CNT_BYTES);

        zero_cnt_kernel<<<(KM_ + 255) / 256, 256, 0, stream>>>(cnt);
        bin_kernel<<<(KNNZ_ + 255) / 256, 256, 0, stream>>>(vals, rows, cols, cnt, slots);
        gather_f32_kernel<<<M_ / 4, 256, 0, stream>>>(x, cnt, slots, (float4*)out);
    } else {
        init_out_kernel<<<(N_ * M_ * FIN_ + 255) / 256, 256, 0, stream>>>(x, out);
        {
            long long tot = (long long)KNNZ_ * 64;
            scatter_kernel<<<(int)((tot + 255) / 256), 256, 0, stream>>>(x, vals, rows, cols, out);
        }
        relu_kernel<<<(N_ * M_ * FIN_ * K_ / 4 + 255) / 256, 256, 0, stream>>>(out);
    }
}

// Round 10
// 452.414 us; speedup vs baseline: 2.6749x; 1.0731x over previous
//
#include <hip/hip_runtime.h>

#define N_    16
#define M_    20000
#define FIN_  64
#define K_    4
#define NNZ_  320000
#define KM_   (K_ * M_)        // 80000
#define KNNZ_ (K_ * NNZ_)      // 1280000
#define CAP_  64               // Poisson(16): P(>64) ~ 1e-19 per bucket

// out[((n*M+m)*FIN+f)*K + k] = relu( x[n,m,f] + sum_{e: rows[k,e]==m} vals[k,e]*x[n,cols[k,e],f] )

// ws layout, tier A:
//   xt    [M_][2][FIN_][8] bf16 @ 0            (xt[m][h][f][n8]; 1KB per (m,h), 2KB per m)
//   cnt   [KM_]        int  @ XT_BYTES
//   slots [KM_*CAP_]   uint @ XT_BYTES+CNT_BYTES   (bf16(val)<<16 | col)
#define XT_BYTES   ((size_t)M_ * FIN_ * N_ * 2)        // 40,960,000
#define CNT_BYTES  ((size_t)KM_ * 4)                   // 320,000
#define SLOT_BYTES ((size_t)KM_ * CAP_ * 4)            // 20,480,000
#define WS_A (XT_BYTES + CNT_BYTES + SLOT_BYTES)       // 61,760,000
#define WS_B (CNT_BYTES + SLOT_BYTES)

__device__ __forceinline__ unsigned bf16bits(float v) {
    unsigned u = __float_as_uint(v);
    return (u + 0x7FFFu + ((u >> 16) & 1u)) & 0xFFFF0000u;   // RNE bf16 in high 16
}

// ---------------- transpose + cnt zeroing ----------------
__global__ __launch_bounds__(256) void transpose_kernel(const float* __restrict__ x,
                                                        uint4* __restrict__ xt4,
                                                        int* __restrict__ cnt) {
    int gtid = blockIdx.x * 256 + threadIdx.x;
    if (gtid < KM_) cnt[gtid] = 0;

    int wid = threadIdx.x >> 6, f = threadIdx.x & 63;
    int m = blockIdx.x * 4 + wid;
    unsigned h[16];
    #pragma unroll
    for (int n = 0; n < N_; ++n)
        h[n] = bf16bits(x[((size_t)n * M_ + m) * FIN_ + f]) >> 16;
    uint4 A, B;
    A.x = h[0]  | (h[1]  << 16); A.y = h[2]  | (h[3]  << 16);
    A.z = h[4]  | (h[5]  << 16); A.w = h[6]  | (h[7]  << 16);
    B.x = h[8]  | (h[9]  << 16); B.y = h[10] | (h[11] << 16);
    B.z = h[12] | (h[13] << 16); B.w = h[14] | (h[15] << 16);
    xt4[m * 128 + f]      = A;   // h = 0 (n 0..7)
    xt4[m * 128 + 64 + f] = B;   // h = 1 (n 8..15)
}

// ---------------- binning ----------------
__global__ void bin_kernel(const float* __restrict__ vals,
                           const int*   __restrict__ rows,
                           const int*   __restrict__ cols,
                           int*      __restrict__ cnt,
                           unsigned* __restrict__ slots) {
    int idx = blockIdx.x * blockDim.x + threadIdx.x;
    if (idx >= KNNZ_) return;
    int k = idx / NNZ_;
    int b = k * M_ + rows[idx];
    int rank = atomicAdd(&cnt[b], 1);
    if (rank < CAP_)
        slots[(size_t)b * CAP_ + rank] = bf16bits(vals[idx]) | (unsigned)cols[idx];
}

// ---------------- tier A gather: block = (m, half); wave = one k ----------------
// 4x the waves of the previous structure; acc is 8 regs; k-recombination via LDS.
__device__ __forceinline__ void fma8(float* a, float v, uint4 U) {
    a[0] += v * __uint_as_float(U.x << 16);
    a[1] += v * __uint_as_float(U.x & 0xFFFF0000u);
    a[2] += v * __uint_as_float(U.y << 16);
    a[3] += v * __uint_as_float(U.y & 0xFFFF0000u);
    a[4] += v * __uint_as_float(U.z << 16);
    a[5] += v * __uint_as_float(U.z & 0xFFFF0000u);
    a[6] += v * __uint_as_float(U.w << 16);
    a[7] += v * __uint_as_float(U.w & 0xFFFF0000u);
}

__global__ __launch_bounds__(256) void gather_bf16_kernel(const char* __restrict__ xtb,
                                                          const int* __restrict__ cnt_arr,
                                                          const unsigned* __restrict__ slots,
                                                          float4* __restrict__ out4) {
    __shared__ float lds[K_][8][64];          // 8 KB
    int k  = threadIdx.x >> 6;                // wave id = k
    int f  = threadIdx.x & 63;
    int m  = blockIdx.x >> 1;
    int hh = blockIdx.x & 1;                  // n-half: n = hh*8 + j
    const char* rowbase = xtb + hh * 1024 + f * 16;   // + c*2048 -> this thread's 16B

    float acc[8];
    {   // identity term (same row for all 4 waves; L1/L2-hot)
        uint4 X = *(const uint4*)(rowbase + ((size_t)m << 11));
        acc[0]=__uint_as_float(X.x<<16); acc[1]=__uint_as_float(X.x&0xFFFF0000u);
        acc[2]=__uint_as_float(X.y<<16); acc[3]=__uint_as_float(X.y&0xFFFF0000u);
        acc[4]=__uint_as_float(X.z<<16); acc[5]=__uint_as_float(X.z&0xFFFF0000u);
        acc[6]=__uint_as_float(X.w<<16); acc[7]=__uint_as_float(X.w&0xFFFF0000u);
    }

    int b  = k * M_ + m;
    int cn = cnt_arr[b];
    if (cn > CAP_) cn = CAP_;
    unsigned sl = slots[(size_t)b * CAP_ + f];   // lane l holds slot l

    for (int g = 0; g < cn; g += 8) {
        uint4 u[8];
        float v[8];
        #pragma unroll
        for (int i = 0; i < 8; ++i) {
            int s = (g + i < cn) ? __shfl((int)sl, g + i, 64) : 0;
            v[i] = __uint_as_float((unsigned)s & 0xFFFF0000u);
            u[i] = *(const uint4*)(rowbase + ((size_t)((unsigned)s & 0xFFFFu) << 11));
        }
        #pragma unroll
        for (int i = 0; i < 8; ++i) fma8(acc, v[i], u[i]);
    }

    // stage per-k partials, then re-assemble float4-over-k stores
    #pragma unroll
    for (int j = 0; j < 8; ++j) lds[k][j][f] = acc[j];
    __syncthreads();

    #pragma unroll
    for (int t = 0; t < 2; ++t) {
        int j = (k << 1) + t;                 // wave k stores rows j=2k,2k+1
        int n = hh * 8 + j;
        float4 w;
        w.x = fmaxf(lds[0][j][f], 0.0f);
        w.y = fmaxf(lds[1][j][f], 0.0f);
        w.z = fmaxf(lds[2][j][f], 0.0f);
        w.w = fmaxf(lds[3][j][f], 0.0f);
        out4[((size_t)n * M_ + m) * FIN_ + f] = w;
    }
}

// ---------------- tier B gather: f32 x directly ----------------
__global__ __launch_bounds__(256) void gather_f32_kernel(const float* __restrict__ x,
                                                         const int* __restrict__ cnt,
                                                         const unsigned* __restrict__ slots,
                                                         float4* __restrict__ out4) {
    int wid = threadIdx.x >> 6;
    int f   = threadIdx.x & 63;
    int m   = blockIdx.x * 4 + wid;

    float acc[K_][N_];
    #pragma unroll
    for (int n = 0; n < N_; ++n) {
        float xv = x[((size_t)n * M_ + m) * FIN_ + f];
        #pragma unroll
        for (int k = 0; k < K_; ++k) acc[k][n] = xv;
    }

    #pragma unroll
    for (int k = 0; k < K_; ++k) {
        int b  = k * M_ + m;
        int cn = cnt[b];
        if (cn > CAP_) cn = CAP_;
        unsigned sl = slots[(size_t)b * CAP_ + f];
        for (int j = 0; j < cn; ++j) {
            int s = __shfl((int)sl, j, 64);
            float v = __uint_as_float((unsigned)s & 0xFFFF0000u);
            int   c = (int)((unsigned)s & 0xFFFFu);
            const float* xp = x + (size_t)c * FIN_ + f;
            #pragma unroll
            for (int n = 0; n < N_; ++n)
                acc[k][n] += v * xp[(size_t)n * (M_ * FIN_)];
        }
    }

    #pragma unroll
    for (int n = 0; n < N_; ++n) {
        float4 w;
        w.x = fmaxf(acc[0][n], 0.0f);
        w.y = fmaxf(acc[1][n], 0.0f);
        w.z = fmaxf(acc[2][n], 0.0f);
        w.w = fmaxf(acc[3][n], 0.0f);
        out4[((size_t)n * M_ + m) * FIN_ + f] = w;
    }
}

__global__ void zero_cnt_kernel(int* __restrict__ cnt) {
    int i = blockIdx.x * blockDim.x + threadIdx.x;
    if (i < KM_) cnt[i] = 0;
}

// ---------------- tier C: atomic fallback ----------------
__global__ void init_out_kernel(const float* __restrict__ x, float* __restrict__ out) {
    int i = blockIdx.x * blockDim.x + threadIdx.x;
    const int tot = N_ * M_ * FIN_;
    if (i < tot) {
        float v = x[i];
        reinterpret_cast<float4*>(out)[i] = make_float4(v, v, v, v);
    }
}

__global__ void scatter_kernel(const float* __restrict__ x,
                               const float* __restrict__ vals,
                               const int*   __restrict__ rows,
                               const int*   __restrict__ cols,
                               float* __restrict__ out) {
    long long idx = (long long)blockIdx.x * blockDim.x + threadIdx.x;
    int f  = (int)(idx & 63);
    int ea = (int)(idx >> 6);
    if (ea >= KNNZ_) return;
    int k = ea / NNZ_;
    float v = vals[ea];
    int r = rows[ea];
    int c = cols[ea];
    const float* xp = x   + (size_t)c * FIN_ + f;
    float*       op = out + ((size_t)r * FIN_ + f) * K_ + k;
    #pragma unroll
    for (int n = 0; n < N_; ++n)
        atomicAdd(op + (size_t)n * (M_ * FIN_ * K_), v * xp[(size_t)n * (M_ * FIN_)]);
}

__global__ void relu_kernel(float* __restrict__ out) {
    int i = blockIdx.x * blockDim.x + threadIdx.x;
    const int tot4 = (N_ * M_ * FIN_ * K_) / 4;
    if (i < tot4) {
        float4 v = reinterpret_cast<float4*>(out)[i];
        v.x = fmaxf(v.x, 0.0f); v.y = fmaxf(v.y, 0.0f);
        v.z = fmaxf(v.z, 0.0f); v.w = fmaxf(v.w, 0.0f);
        reinterpret_cast<float4*>(out)[i] = v;
    }
}

// ---------------- launch ----------------
extern "C" void kernel_launch(void* const* d_in, const int* in_sizes, int n_in,
                              void* d_out, int out_size, void* d_ws, size_t ws_size,
                              hipStream_t stream) {
    const float* x    = (const float*)d_in[0];
    const float* vals = (const float*)d_in[1];
    const int*   rows = (const int*)d_in[2];
    const int*   cols = (const int*)d_in[3];
    float*       out  = (float*)d_out;
    char*        ws   = (char*)d_ws;

    if (ws_size >= WS_A) {
        uint4*    xt4   = (uint4*)ws;
        int*      cnt   = (int*)(ws + XT_BYTES);
        unsigned* slots = (unsigned*)(ws + XT_BYTES + CNT_BYTES);

        transpose_kernel<<<M_ / 4, 256, 0, stream>>>(x, xt4, cnt);
        bin_kernel<<<(KNNZ_ + 255) / 256, 256, 0, stream>>>(vals, rows, cols, cnt, slots);
        gather_bf16_kernel<<<M_ * 2, 256, 0, stream>>>((const char*)ws, cnt, slots, (float4*)out);
    } else if (ws_size >= WS_B) {
        int*      cnt   = (int*)ws;
        unsigned* slots = (unsigned*)(ws + CNT_BYTES);

        zero_cnt_kernel<<<(KM_ + 255) / 256, 256, 0, stream>>>(cnt);
        bin_kernel<<<(KNNZ_ + 255) / 256, 256, 0, stream>>>(vals, rows, cols, cnt, slots);
        gather_f32_kernel<<<M_ / 4, 256, 0, stream>>>(x, cnt, slots, (float4*)out);
    } else {
        init_out_kernel<<<(N_ * M_ * FIN_ + 255) / 256, 256, 0, stream>>>(x, out);
        {
            long long tot = (long long)KNNZ_ * 64;
            scatter_kernel<<<(int)((tot + 255) / 256), 256, 0, stream>>>(x, vals, rows, cols, out);
        }
        relu_kernel<<<(N_ * M_ * FIN_ * K_ / 4 + 255) / 256, 256, 0, stream>>>(out);
    }
}